// Round 2
// baseline (2104.062 us; speedup 1.0000x reference)
//
#include <hip/hip_runtime.h>
#include <hip/hip_bf16.h>
#include <stdint.h>

// R1: adaptive workspace. Big path (~520MB ws) = single-shot dense pipeline.
// Chunked path (~75MB ws) = per-unit (expert / shared-slice) loop with reused
// buffers and accumulating down-GEMM. Same MFMA core everywhere.

typedef float f32x4 __attribute__((ext_vector_type(4)));
typedef int   i32x4 __attribute__((ext_vector_type(4)));
typedef __hip_bfloat16 bf16;

#define DEV __device__ __forceinline__

DEV void mfma16(f32x4& c, const i32x4& a, const i32x4& b) {
    // D[m][n]: m=(l>>4)*4+r, n=l&15 (m89-verified). A/B frags: row l&15,
    // 8 contiguous bf16 along K — consistent A/B k-permutation is exact.
    asm("v_mfma_f32_16x16x32_bf16 %0, %1, %2, %0" : "+v"(c) : "v"(a), "v"(b));
}

// Stage a [ROWS][64] bf16 tile (row-major, row=128B) into LDS linearly via
// global_load_lds width 16, with the T2 XOR swizzle applied on the GLOBAL
// source (rule #21: linear dest + inverse-swz source + swz on read).
template<int ROWS>
DEV void stage(const bf16* gtile, long ldK, char* lds, int tid) {
    const int wid = tid >> 6, lane = tid & 63;
    const int swz = ((lane & 7) ^ (lane >> 3)) << 4;   // pre-swizzled inner byte
    constexpr int NISS = (ROWS * 128) / 4096;
    #pragma unroll
    for (int i = 0; i < NISS; i++) {
        const int o = i * 4096 + wid * 1024;           // wave-uniform LDS base
        const int row = (o >> 7) + (lane >> 3);        // (o>>7) % 8 == 0
        const char* ga = (const char*)gtile + (long)row * (ldK * 2) + swz;
        __builtin_amdgcn_global_load_lds(
            (const __attribute__((address_space(1))) void*)ga,
            (__attribute__((address_space(3))) void*)(lds + o), 16, 0, 0);
    }
}

// Swizzled ds_read_b128 of one MFMA fragment (8 bf16 along K at tile row).
DEV i32x4 ldsfrag(const char* lds, int row, int kbyte) {
    const int off = (row << 7) + (kbyte ^ ((row & 7) << 4));
    return *(const i32x4*)(lds + off);
}

// ---------------- transpose + fp32->bf16 convert ----------------
// dst[(cb+c)*dld + dcol + rb+tx] = src[(rb+r)*Cd + cb+tx]; grid z adds
// z*sz (elems) to src and z*dz (elems) to dst.
__global__ __launch_bounds__(256) void tcvt(const float* __restrict__ src,
        bf16* __restrict__ dst, int R, int Cd, long dld, long dcol,
        long sz, long dz) {
    __shared__ float t[64][65];
    const long z = blockIdx.z;
    src += z * sz; dst += z * dz;
    const int cb = blockIdx.x * 64, rb = blockIdx.y * 64;
    const int tx = threadIdx.x & 63, ty = threadIdx.x >> 6;
    #pragma unroll
    for (int i = 0; i < 16; i++) {
        const int r = ty + i * 4;
        t[r][tx] = src[(long)(rb + r) * Cd + cb + tx];
    }
    __syncthreads();
    #pragma unroll
    for (int i = 0; i < 16; i++) {
        const int c = ty + i * 4;
        dst[(long)(cb + c) * dld + dcol + rb + tx] = __float2bfloat16(t[tx][c]);
    }
}

// ---------------- x fp32 -> bf16 ----------------
__global__ __launch_bounds__(256) void cvtx(const float* __restrict__ x,
        bf16* __restrict__ xb, long n4) {
    long i = (long)blockIdx.x * blockDim.x + threadIdx.x;
    const long stride = (long)gridDim.x * blockDim.x;
    for (; i < n4; i += stride) {
        const float4 v = ((const float4*)x)[i];
        union { bf16 h[4]; ushort4 u; } cu;
        cu.h[0] = __float2bfloat16(v.x); cu.h[1] = __float2bfloat16(v.y);
        cu.h[2] = __float2bfloat16(v.z); cu.h[3] = __float2bfloat16(v.w);
        ((ushort4*)xb)[i] = cu.u;
    }
}

// ---------------- router: fp32 logits, softmax, top-4, renorm ----------------
__global__ __launch_bounds__(256) void router(const float* __restrict__ x,
        const float* __restrict__ gw, const float* __restrict__ segw,
        float* __restrict__ gates, float* __restrict__ sg, int C) {
    const int lane = threadIdx.x & 63;
    const long t = (long)blockIdx.x * 4 + (threadIdx.x >> 6);
    const float* xr = x + t * C;
    float a[9];
    #pragma unroll
    for (int e = 0; e < 9; e++) a[e] = 0.f;
    for (int c = lane; c < C; c += 64) {
        const float xv = xr[c];
        const float4* g4 = (const float4*)(gw + (long)c * 8);
        const float4 g0 = g4[0], g1 = g4[1];
        a[0] += xv * g0.x; a[1] += xv * g0.y; a[2] += xv * g0.z; a[3] += xv * g0.w;
        a[4] += xv * g1.x; a[5] += xv * g1.y; a[6] += xv * g1.z; a[7] += xv * g1.w;
        a[8] += xv * segw[c];
    }
    #pragma unroll
    for (int e = 0; e < 9; e++) {
        #pragma unroll
        for (int o = 32; o; o >>= 1) a[e] += __shfl_xor(a[e], o, 64);
    }
    if (lane == 0) {
        float m = a[0];
        #pragma unroll
        for (int e = 1; e < 8; e++) m = fmaxf(m, a[e]);
        float p[8]; float s = 0.f;
        #pragma unroll
        for (int e = 0; e < 8; e++) { p[e] = expf(a[e] - m); s += p[e]; }
        #pragma unroll
        for (int e = 0; e < 8; e++) p[e] /= s;
        bool used[8] = {false,false,false,false,false,false,false,false};
        float g8[8]  = {0,0,0,0,0,0,0,0};
        float wsum = 0.f; int idx[4]; float wv[4];
        for (int k = 0; k < 4; k++) {       // strict > : lowest index on ties
            float best = -1.f; int bi = 0;
            for (int e = 0; e < 8; e++)
                if (!used[e] && p[e] > best) { best = p[e]; bi = e; }
            used[bi] = true; idx[k] = bi; wv[k] = best; wsum += best;
        }
        for (int k = 0; k < 4; k++) g8[idx[k]] = wv[k] / wsum;
        #pragma unroll
        for (int e = 0; e < 8; e++) gates[t * 8 + e] = g8[e];
        sg[t] = 1.f / (1.f + expf(-a[8]));
    }
}

// ---------------- fused gate+up GEMM: H = silu(A BG^T)*(A BU^T)*scale ------
// Tile 128x64, BK=64, 4 waves (2x2); both B matrices share the A tile.
__global__ __launch_bounds__(256) void dual_gemm(const bf16* __restrict__ A,
        const bf16* __restrict__ BG0, const bf16* __restrict__ BU0, long bz,
        bf16* __restrict__ H, long hld, long hcol0, long hcolz,
        const float* __restrict__ sc, int scm, int scz, int K) {
    __shared__ __align__(128) char Al[16384];
    __shared__ __align__(128) char Gl[8192];
    __shared__ __align__(128) char Ul[8192];
    const int tid = threadIdx.x, lane = tid & 63, wid = tid >> 6;
    const int z = blockIdx.z;
    const bf16* BG = BG0 + (long)z * bz;
    const bf16* BU = BU0 + (long)z * bz;
    const long m0 = (long)blockIdx.x * 128;
    const long n0 = (long)blockIdx.y * 64;
    const long hc = hcol0 + (long)z * hcolz + n0;
    const int wm = (wid >> 1) * 64, wn = (wid & 1) * 32;
    const int l15 = lane & 15, lhi = lane >> 4;
    f32x4 ag[4][2] = {}; f32x4 au[4][2] = {};
    for (int kt = 0; kt < K; kt += 64) {
        stage<128>(A  + m0 * K + kt, (long)K, Al, tid);
        stage<64> (BG + n0 * K + kt, (long)K, Gl, tid);
        stage<64> (BU + n0 * K + kt, (long)K, Ul, tid);
        __syncthreads();
        #pragma unroll
        for (int ks = 0; ks < 2; ks++) {
            const int kb = ks * 64 + lhi * 16;
            i32x4 af[4], bg[2], bu[2];
            #pragma unroll
            for (int mi = 0; mi < 4; mi++) af[mi] = ldsfrag(Al, wm + mi * 16 + l15, kb);
            #pragma unroll
            for (int ni = 0; ni < 2; ni++) {
                bg[ni] = ldsfrag(Gl, wn + ni * 16 + l15, kb);
                bu[ni] = ldsfrag(Ul, wn + ni * 16 + l15, kb);
            }
            #pragma unroll
            for (int mi = 0; mi < 4; mi++) {
                #pragma unroll
                for (int ni = 0; ni < 2; ni++) {
                    mfma16(ag[mi][ni], af[mi], bg[ni]);
                    mfma16(au[mi][ni], af[mi], bu[ni]);
                }
            }
        }
        __syncthreads();
    }
    asm volatile("s_nop 7\n\ts_nop 7\n\ts_nop 7");   // MFMA->VALU hazard guard
    #pragma unroll
    for (int mi = 0; mi < 4; mi++) {
        #pragma unroll
        for (int r = 0; r < 4; r++) {
            const long row = m0 + wm + mi * 16 + lhi * 4 + r;
            const float s = sc[row * scm + (long)z * scz];
            #pragma unroll
            for (int ni = 0; ni < 2; ni++) {
                const float gv = ag[mi][ni][r], uv = au[mi][ni][r];
                const float h = (gv / (1.f + expf(-gv))) * uv * s;
                H[row * hld + hc + wn + ni * 16 + l15] = __float2bfloat16(h);
            }
        }
    }
}

// ---------------- down GEMM: C[M,N] (+)= A[M,K] * BT[N,K]^T ----------------
// Tile 128x128, BK=64, 4 waves (2x2).
__global__ __launch_bounds__(256) void gemm_down(const bf16* __restrict__ A,
        const bf16* __restrict__ BT, float* __restrict__ C, int K, long ldc,
        int beta) {
    __shared__ __align__(128) char Al[16384];
    __shared__ __align__(128) char Bl[16384];
    const int tid = threadIdx.x, lane = tid & 63, wid = tid >> 6;
    const long m0 = (long)blockIdx.y * 128;
    const long n0 = (long)blockIdx.x * 128;
    const int wm = (wid >> 1) * 64, wn = (wid & 1) * 64;
    const int l15 = lane & 15, lhi = lane >> 4;
    f32x4 acc[4][4] = {};
    for (int kt = 0; kt < K; kt += 64) {
        stage<128>(A  + m0 * K + kt, (long)K, Al, tid);
        stage<128>(BT + n0 * K + kt, (long)K, Bl, tid);
        __syncthreads();
        #pragma unroll
        for (int ks = 0; ks < 2; ks++) {
            const int kb = ks * 64 + lhi * 16;
            i32x4 af[4], bfr[4];
            #pragma unroll
            for (int mi = 0; mi < 4; mi++) af[mi]  = ldsfrag(Al, wm + mi * 16 + l15, kb);
            #pragma unroll
            for (int ni = 0; ni < 4; ni++) bfr[ni] = ldsfrag(Bl, wn + ni * 16 + l15, kb);
            #pragma unroll
            for (int mi = 0; mi < 4; mi++) {
                #pragma unroll
                for (int ni = 0; ni < 4; ni++) mfma16(acc[mi][ni], af[mi], bfr[ni]);
            }
        }
        __syncthreads();
    }
    asm volatile("s_nop 7\n\ts_nop 7\n\ts_nop 7");
    #pragma unroll
    for (int mi = 0; mi < 4; mi++) {
        #pragma unroll
        for (int ni = 0; ni < 4; ni++) {
            #pragma unroll
            for (int r = 0; r < 4; r++) {
                const long ci = (m0 + wm + mi * 16 + lhi * 4 + r) * ldc
                              + n0 + wn + ni * 16 + l15;
                float v = acc[mi][ni][r];
                if (beta) v += C[ci];
                C[ci] = v;
            }
        }
    }
}

extern "C" void kernel_launch(void* const* d_in, const int* in_sizes, int n_in,
                              void* d_out, int out_size, void* d_ws, size_t ws_size,
                              hipStream_t stream) {
    const int N = 8192, Cdim = 2048, E = 8, I = 1408, SI = 5632;
    const long KH = (long)E * I + SI;   // 16896

    const float* x    = (const float*)d_in[0];
    const float* gw   = (const float*)d_in[1];
    const float* egw  = (const float*)d_in[2];
    const float* euw  = (const float*)d_in[3];
    const float* edw  = (const float*)d_in[4];
    const float* sgw  = (const float*)d_in[5];
    const float* suw  = (const float*)d_in[6];
    const float* sdw  = (const float*)d_in[7];
    const float* segw = (const float*)d_in[8];

    char* ws = (char*)d_ws;
    size_t off = 0;
    auto alloc = [&](size_t bytes) { char* p = ws + off; off += (bytes + 255) & ~(size_t)255; return p; };

    // Common small buffers + xb.
    bf16*  xb    = (bf16*) alloc((size_t)N * Cdim * 2);            // 33.6 MB
    float* gates = (float*)alloc((size_t)N * E * 4);
    float* sg    = (float*)alloc((size_t)N * 4);
    const size_t commonEnd = off;

    cvtx<<<4096, 256, 0, stream>>>(x, xb, (long)N * Cdim / 4);
    router<<<N / 4, 256, 0, stream>>>(x, gw, segw, gates, sg, Cdim);

    // ---- big-path footprint check ----
    const size_t bigNeed = commonEnd
        + 2 * (size_t)E * I * Cdim * 2    // WgT, WuT
        + 2 * (size_t)SI * Cdim * 2       // WsgT, WsuT
        + (size_t)Cdim * KH * 2           // WdT
        + (size_t)N * KH * 2              // H
        + 4096;

    if (ws_size >= bigNeed) {
        bf16* WgT  = (bf16*)alloc((size_t)E * I * Cdim * 2);   // [E][I][C]
        bf16* WuT  = (bf16*)alloc((size_t)E * I * Cdim * 2);
        bf16* WsgT = (bf16*)alloc((size_t)SI * Cdim * 2);      // [SI][C]
        bf16* WsuT = (bf16*)alloc((size_t)SI * Cdim * 2);
        bf16* WdT  = (bf16*)alloc((size_t)Cdim * KH * 2);      // [C][16896]
        bf16* H    = (bf16*)alloc((size_t)N * KH * 2);         // [N][16896]

        tcvt<<<dim3(I / 64,    Cdim / 64, E), 256, 0, stream>>>(egw, WgT,  Cdim, I,    (long)Cdim, 0,      (long)Cdim * I, (long)I * Cdim);
        tcvt<<<dim3(I / 64,    Cdim / 64, E), 256, 0, stream>>>(euw, WuT,  Cdim, I,    (long)Cdim, 0,      (long)Cdim * I, (long)I * Cdim);
        tcvt<<<dim3(SI / 64,   Cdim / 64, 1), 256, 0, stream>>>(sgw, WsgT, Cdim, SI,   (long)Cdim, 0,      0, 0);
        tcvt<<<dim3(SI / 64,   Cdim / 64, 1), 256, 0, stream>>>(suw, WsuT, Cdim, SI,   (long)Cdim, 0,      0, 0);
        tcvt<<<dim3(Cdim / 64, I / 64,    E), 256, 0, stream>>>(edw, WdT,  I,    Cdim, KH,         0,      (long)I * Cdim, (long)I);
        tcvt<<<dim3(Cdim / 64, SI / 64,   1), 256, 0, stream>>>(sdw, WdT,  SI,   Cdim, KH,         (long)E * I, 0, 0);

        dual_gemm<<<dim3(N / 128, I / 64,  E), 256, 0, stream>>>(xb, WgT,  WuT,  (long)I * Cdim,
                H, KH, 0,            (long)I, gates, E, 1, Cdim);
        dual_gemm<<<dim3(N / 128, SI / 64, 1), 256, 0, stream>>>(xb, WsgT, WsuT, 0,
                H, KH, (long)E * I,  0,       sg,    1, 0, Cdim);

        gemm_down<<<dim3(Cdim / 128, N / 128), 256, 0, stream>>>(H, WdT, (float*)d_out, (int)KH, (long)Cdim, 0);
        return;
    }

    // ---- chunked path: units of intermediate width ch, reused buffers ----
    auto need = [&](int ch) {
        return commonEnd + (size_t)ch * Cdim * 2 * 3     // Wg, Wu, Wd
             + (size_t)N * ch * 2 + 4096;                // Hc
    };
    const int ch = (ws_size >= need(1408)) ? 1408 : 704;
    if (ws_size < need(704)) return;    // cannot run: <54MB scratch

    bf16* Wg = (bf16*)alloc((size_t)ch * Cdim * 2);
    bf16* Wu = (bf16*)alloc((size_t)ch * Cdim * 2);
    bf16* Wd = (bf16*)alloc((size_t)ch * Cdim * 2);   // [C][ch] actually; same size
    bf16* Hc = (bf16*)alloc((size_t)N * ch * 2);

    hipMemsetAsync(d_out, 0, (size_t)N * Cdim * 4, stream);

    const int nExpChunks = I / ch, nShChunks = SI / ch;
    for (int u = 0; u < E * nExpChunks + nShChunks; u++) {
        const bool isExp = u < E * nExpChunks;
        const int e = isExp ? u / nExpChunks : 0;
        const int s = isExp ? u % nExpChunks : u - E * nExpChunks;
        const long col0 = (long)s * ch;
        const float* gsrc = isExp ? egw + (long)e * Cdim * I + col0 : sgw + col0;
        const float* usrc = isExp ? euw + (long)e * Cdim * I + col0 : suw + col0;
        const float* dsrc = isExp ? edw + (long)e * I * Cdim + col0 * Cdim
                                  : sdw + col0 * Cdim;
        const int srcStride = isExp ? I : SI;
        const float* scp = isExp ? gates + e : sg;
        const int scm = isExp ? E : 1;

        tcvt<<<dim3(ch / 64, Cdim / 64, 1), 256, 0, stream>>>(gsrc, Wg, Cdim, srcStride, (long)Cdim, 0, 0, 0);
        tcvt<<<dim3(ch / 64, Cdim / 64, 1), 256, 0, stream>>>(usrc, Wu, Cdim, srcStride, (long)Cdim, 0, 0, 0);
        dual_gemm<<<dim3(N / 128, ch / 64, 1), 256, 0, stream>>>(xb, Wg, Wu, 0,
                Hc, (long)ch, 0, 0, scp, scm, 0, Cdim);
        tcvt<<<dim3(Cdim / 64, ch / 64, 1), 256, 0, stream>>>(dsrc, Wd, ch, Cdim, (long)ch, 0, 0, 0);
        gemm_down<<<dim3(Cdim / 128, N / 128), 256, 0, stream>>>(Hc, Wd, (float*)d_out, ch, (long)Cdim, 1);
    }
}

// Round 3
// 1724.084 us; speedup vs baseline: 1.2204x; 1.2204x over previous
//
#include <hip/hip_runtime.h>
#include <hip/hip_bf16.h>
#include <stdint.h>

// R2: sparse top-4 dispatch. Router -> per-expert token lists (deterministic
// prefix scan) -> gathered dual gate/up GEMM (indirect A staging) -> scatter-
// accumulating down GEMM in fixed expert order. Shared expert runs first with
// beta=0 (covers d_out, no memset). Same MFMA core as R1 (verified).

typedef float f32x4 __attribute__((ext_vector_type(4)));
typedef int   i32x4 __attribute__((ext_vector_type(4)));
typedef __hip_bfloat16 bf16;

#define DEV __device__ __forceinline__

DEV void mfma16(f32x4& c, const i32x4& a, const i32x4& b) {
    asm("v_mfma_f32_16x16x32_bf16 %0, %1, %2, %0" : "+v"(c) : "v"(a), "v"(b));
}

// Direct stage: [ROWS][64] bf16 tile (row stride ldK elems) -> LDS linear,
// T2 XOR swizzle applied on the global source (rule #21).
template<int ROWS>
DEV void stage(const bf16* gtile, long ldK, char* lds, int tid) {
    const int wid = tid >> 6, lane = tid & 63;
    const int swz = ((lane & 7) ^ (lane >> 3)) << 4;
    constexpr int NISS = (ROWS * 128) / 4096;
    #pragma unroll
    for (int i = 0; i < NISS; i++) {
        const int o = i * 4096 + wid * 1024;
        const int row = (o >> 7) + (lane >> 3);
        const char* ga = (const char*)gtile + (long)row * (ldK * 2) + swz;
        __builtin_amdgcn_global_load_lds(
            (const __attribute__((address_space(1))) void*)ga,
            (__attribute__((address_space(3))) void*)(lds + o), 16, 0, 0);
    }
}

// Indirect stage: per-lane row byte-offsets precomputed (gathered rows).
template<int ROWS>
DEV void stage_idx(const char* base, const long* roff, int ktb, char* lds,
                   int tid, int swz) {
    const int wid = tid >> 6;
    constexpr int NISS = (ROWS * 128) / 4096;
    #pragma unroll
    for (int i = 0; i < NISS; i++) {
        const int o = i * 4096 + wid * 1024;
        const char* ga = base + roff[i] + ktb + swz;
        __builtin_amdgcn_global_load_lds(
            (const __attribute__((address_space(1))) void*)ga,
            (__attribute__((address_space(3))) void*)(lds + o), 16, 0, 0);
    }
}

DEV i32x4 ldsfrag(const char* lds, int row, int kbyte) {
    const int off = (row << 7) + (kbyte ^ ((row & 7) << 4));
    return *(const i32x4*)(lds + off);
}

// ---------------- transpose + fp32->bf16 convert ----------------
// dst[(cb+c)*dld + rb+tx] = src[(rb+r)*Cd + cb+tx]   (Cd = src row stride)
__global__ __launch_bounds__(256) void tcvt(const float* __restrict__ src,
        bf16* __restrict__ dst, int Cd, long dld) {
    __shared__ float t[64][65];
    const int cb = blockIdx.x * 64, rb = blockIdx.y * 64;
    const int tx = threadIdx.x & 63, ty = threadIdx.x >> 6;
    #pragma unroll
    for (int i = 0; i < 16; i++) {
        const int r = ty + i * 4;
        t[r][tx] = src[(long)(rb + r) * Cd + cb + tx];
    }
    __syncthreads();
    #pragma unroll
    for (int i = 0; i < 16; i++) {
        const int c = ty + i * 4;
        dst[(long)(cb + c) * dld + rb + tx] = __float2bfloat16(t[tx][c]);
    }
}

// ---------------- x fp32 -> bf16 ----------------
__global__ __launch_bounds__(256) void cvtx(const float* __restrict__ x,
        bf16* __restrict__ xb, long n4) {
    long i = (long)blockIdx.x * blockDim.x + threadIdx.x;
    const long stride = (long)gridDim.x * blockDim.x;
    for (; i < n4; i += stride) {
        const float4 v = ((const float4*)x)[i];
        union { bf16 h[4]; ushort4 u; } cu;
        cu.h[0] = __float2bfloat16(v.x); cu.h[1] = __float2bfloat16(v.y);
        cu.h[2] = __float2bfloat16(v.z); cu.h[3] = __float2bfloat16(v.w);
        ((ushort4*)xb)[i] = cu.u;
    }
}

// ---------------- router: fp32 logits, softmax, top-4, renorm ----------------
__global__ __launch_bounds__(256) void router(const float* __restrict__ x,
        const float* __restrict__ gw, const float* __restrict__ segw,
        int* __restrict__ tidx, float* __restrict__ tw,
        float* __restrict__ sg, int C) {
    const int lane = threadIdx.x & 63;
    const long t = (long)blockIdx.x * 4 + (threadIdx.x >> 6);
    const float* xr = x + t * C;
    float a[9];
    #pragma unroll
    for (int e = 0; e < 9; e++) a[e] = 0.f;
    for (int c = lane; c < C; c += 64) {
        const float xv = xr[c];
        const float4* g4 = (const float4*)(gw + (long)c * 8);
        const float4 g0 = g4[0], g1 = g4[1];
        a[0] += xv * g0.x; a[1] += xv * g0.y; a[2] += xv * g0.z; a[3] += xv * g0.w;
        a[4] += xv * g1.x; a[5] += xv * g1.y; a[6] += xv * g1.z; a[7] += xv * g1.w;
        a[8] += xv * segw[c];
    }
    #pragma unroll
    for (int e = 0; e < 9; e++) {
        #pragma unroll
        for (int o = 32; o; o >>= 1) a[e] += __shfl_xor(a[e], o, 64);
    }
    if (lane == 0) {
        float m = a[0];
        #pragma unroll
        for (int e = 1; e < 8; e++) m = fmaxf(m, a[e]);
        float p[8]; float s = 0.f;
        #pragma unroll
        for (int e = 0; e < 8; e++) { p[e] = expf(a[e] - m); s += p[e]; }
        #pragma unroll
        for (int e = 0; e < 8; e++) p[e] /= s;
        bool used[8] = {false,false,false,false,false,false,false,false};
        float wsum = 0.f; int idx[4]; float wv[4];
        for (int k = 0; k < 4; k++) {       // strict > : lowest index on ties
            float best = -1.f; int bi = 0;
            for (int e = 0; e < 8; e++)
                if (!used[e] && p[e] > best) { best = p[e]; bi = e; }
            used[bi] = true; idx[k] = bi; wv[k] = best; wsum += best;
        }
        int4 iv; float4 wv4;
        iv.x = idx[0]; iv.y = idx[1]; iv.z = idx[2]; iv.w = idx[3];
        wv4.x = wv[0] / wsum; wv4.y = wv[1] / wsum;
        wv4.z = wv[2] / wsum; wv4.w = wv[3] / wsum;
        ((int4*)tidx)[t] = iv;
        ((float4*)tw)[t] = wv4;
        sg[t] = 1.f / (1.f + expf(-a[8]));
    }
}

// ---------------- per-expert ordered token lists (deterministic) ------------
__global__ __launch_bounds__(256) void build_lists(const int* __restrict__ tidx,
        const float* __restrict__ tw, int* __restrict__ tok,
        float* __restrict__ wl, int* __restrict__ cnt, int N) {
    const int e = blockIdx.x;                 // 8 blocks
    const int tid = threadIdx.x;
    const int per = N / 256;                  // 32 tokens/thread, contiguous
    __shared__ int csum[256];
    int c = 0;
    for (int i = 0; i < per; i++) {
        const int4 id4 = ((const int4*)tidx)[tid * per + i];
        if (id4.x == e || id4.y == e || id4.z == e || id4.w == e) c++;
    }
    csum[tid] = c;
    __syncthreads();
    for (int o = 1; o < 256; o <<= 1) {       // Hillis-Steele inclusive scan
        const int v = (tid >= o) ? csum[tid - o] : 0;
        __syncthreads();
        csum[tid] += v;
        __syncthreads();
    }
    int pos = csum[tid] - c;                  // exclusive prefix
    if (tid == 255) cnt[e] = csum[255];
    for (int i = 0; i < per; i++) {
        const int t = tid * per + i;
        const int4   id4 = ((const int4*)tidx)[t];
        const float4 w4  = ((const float4*)tw)[t];
        float w = 0.f; int hit = 0;
        if      (id4.x == e) { w = w4.x; hit = 1; }
        else if (id4.y == e) { w = w4.y; hit = 1; }
        else if (id4.z == e) { w = w4.z; hit = 1; }
        else if (id4.w == e) { w = w4.w; hit = 1; }
        if (hit) { tok[(long)e * N + pos] = t; wl[(long)e * N + pos] = w; pos++; }
    }
}

// -------- fused gate+up GEMM: H[pos] = silu(xg)*xu*sc[pos], gathered A ------
// Tile 128x64, BK=64, 4 waves (2x2). ridx!=null -> A rows gathered.
__global__ __launch_bounds__(256) void dual_gemm(const bf16* __restrict__ A,
        const int* __restrict__ ridx, const int* __restrict__ cntp, int Mfix,
        const bf16* __restrict__ BG, const bf16* __restrict__ BU,
        bf16* __restrict__ H, long hld,
        const float* __restrict__ sc, int K) {
    __shared__ __align__(128) char Al[16384];
    __shared__ __align__(128) char Gl[8192];
    __shared__ __align__(128) char Ul[8192];
    const int Me = cntp ? *cntp : Mfix;
    const long m0 = (long)blockIdx.x * 128;
    if (m0 >= Me) return;
    const int tid = threadIdx.x, lane = tid & 63, wid = tid >> 6;
    const long n0 = (long)blockIdx.y * 64;
    const int wm = (wid >> 1) * 64, wn = (wid & 1) * 32;
    const int l15 = lane & 15, lhi = lane >> 4;
    const int swz = ((lane & 7) ^ (lane >> 3)) << 4;
    long roffA[4];
    #pragma unroll
    for (int i = 0; i < 4; i++) {
        const int rit = ((i * 4096 + wid * 1024) >> 7) + (lane >> 3);
        int g = (int)m0 + rit;
        if (ridx) g = ridx[g < Me ? g : Me - 1];
        roffA[i] = (long)g * (K * 2);
    }
    f32x4 ag[4][2] = {}; f32x4 au[4][2] = {};
    for (int kt = 0; kt < K; kt += 64) {
        stage_idx<128>((const char*)A, roffA, kt * 2, Al, tid, swz);
        stage<64>(BG + n0 * K + kt, (long)K, Gl, tid);
        stage<64>(BU + n0 * K + kt, (long)K, Ul, tid);
        __syncthreads();
        #pragma unroll
        for (int ks = 0; ks < 2; ks++) {
            const int kb = ks * 64 + lhi * 16;
            i32x4 af[4], bg[2], bu[2];
            #pragma unroll
            for (int mi = 0; mi < 4; mi++) af[mi] = ldsfrag(Al, wm + mi * 16 + l15, kb);
            #pragma unroll
            for (int ni = 0; ni < 2; ni++) {
                bg[ni] = ldsfrag(Gl, wn + ni * 16 + l15, kb);
                bu[ni] = ldsfrag(Ul, wn + ni * 16 + l15, kb);
            }
            #pragma unroll
            for (int mi = 0; mi < 4; mi++) {
                #pragma unroll
                for (int ni = 0; ni < 2; ni++) {
                    mfma16(ag[mi][ni], af[mi], bg[ni]);
                    mfma16(au[mi][ni], af[mi], bu[ni]);
                }
            }
        }
        __syncthreads();
    }
    asm volatile("s_nop 7\n\ts_nop 7\n\ts_nop 7");
    #pragma unroll
    for (int mi = 0; mi < 4; mi++) {
        #pragma unroll
        for (int r = 0; r < 4; r++) {
            const int pos = (int)m0 + wm + mi * 16 + lhi * 4 + r;
            if (pos < Me) {
                const float s = sc[pos];
                #pragma unroll
                for (int ni = 0; ni < 2; ni++) {
                    const float gv = ag[mi][ni][r], uv = au[mi][ni][r];
                    const float h = (gv / (1.f + expf(-gv))) * uv * s;
                    H[(long)pos * hld + n0 + wn + ni * 16 + l15] = __float2bfloat16(h);
                }
            }
        }
    }
}

// ------ down GEMM: C[row(pos)] (+)= A[pos,:K] * BT^T, scatter rows ----------
// Tile 128x128, BK=64, 4 waves (2x2).
__global__ __launch_bounds__(256) void gemm_down(const bf16* __restrict__ A,
        const bf16* __restrict__ BT, float* __restrict__ C,
        const int* __restrict__ ridx, const int* __restrict__ cntp, int Mfix,
        int K, long ldc, int beta) {
    __shared__ __align__(128) char Al[16384];
    __shared__ __align__(128) char Bl[16384];
    const int Me = cntp ? *cntp : Mfix;
    const long m0 = (long)blockIdx.y * 128;
    if (m0 >= Me) return;
    const int tid = threadIdx.x, lane = tid & 63, wid = tid >> 6;
    const long n0 = (long)blockIdx.x * 128;
    const int wm = (wid >> 1) * 64, wn = (wid & 1) * 64;
    const int l15 = lane & 15, lhi = lane >> 4;
    f32x4 acc[4][4] = {};
    for (int kt = 0; kt < K; kt += 64) {
        stage<128>(A  + m0 * K + kt, (long)K, Al, tid);
        stage<128>(BT + n0 * K + kt, (long)K, Bl, tid);
        __syncthreads();
        #pragma unroll
        for (int ks = 0; ks < 2; ks++) {
            const int kb = ks * 64 + lhi * 16;
            i32x4 af[4], bfr[4];
            #pragma unroll
            for (int mi = 0; mi < 4; mi++) af[mi]  = ldsfrag(Al, wm + mi * 16 + l15, kb);
            #pragma unroll
            for (int ni = 0; ni < 4; ni++) bfr[ni] = ldsfrag(Bl, wn + ni * 16 + l15, kb);
            #pragma unroll
            for (int mi = 0; mi < 4; mi++) {
                #pragma unroll
                for (int ni = 0; ni < 4; ni++) mfma16(acc[mi][ni], af[mi], bfr[ni]);
            }
        }
        __syncthreads();
    }
    asm volatile("s_nop 7\n\ts_nop 7\n\ts_nop 7");
    #pragma unroll
    for (int mi = 0; mi < 4; mi++) {
        #pragma unroll
        for (int r = 0; r < 4; r++) {
            const int pos = (int)m0 + wm + mi * 16 + lhi * 4 + r;
            if (pos < Me) {
                const long orow = ridx ? (long)ridx[pos] : (long)pos;
                #pragma unroll
                for (int ni = 0; ni < 4; ni++) {
                    const long ci = orow * ldc + n0 + wn + ni * 16 + l15;
                    float v = acc[mi][ni][r];
                    if (beta) v += C[ci];
                    C[ci] = v;
                }
            }
        }
    }
}

extern "C" void kernel_launch(void* const* d_in, const int* in_sizes, int n_in,
                              void* d_out, int out_size, void* d_ws, size_t ws_size,
                              hipStream_t stream) {
    const int N = 8192, Cdim = 2048, E = 8, I = 1408, SI = 5632;

    const float* x    = (const float*)d_in[0];
    const float* gw   = (const float*)d_in[1];
    const float* egw  = (const float*)d_in[2];
    const float* euw  = (const float*)d_in[3];
    const float* edw  = (const float*)d_in[4];
    const float* sgw  = (const float*)d_in[5];
    const float* suw  = (const float*)d_in[6];
    const float* sdw  = (const float*)d_in[7];
    const float* segw = (const float*)d_in[8];
    float* out = (float*)d_out;

    char* ws = (char*)d_ws;
    size_t off = 0;
    auto alloc = [&](size_t bytes) { char* p = ws + off; off += (bytes + 255) & ~(size_t)255; return p; };

    bf16*  xb   = (bf16*) alloc((size_t)N * Cdim * 2);   // 33.6 MB
    int*   tidx = (int*)  alloc((size_t)N * 4 * 4);
    float* tw   = (float*)alloc((size_t)N * 4 * 4);
    float* sg   = (float*)alloc((size_t)N * 4);
    int*   tok  = (int*)  alloc((size_t)E * N * 4);
    float* wl   = (float*)alloc((size_t)E * N * 4);
    int*   cnt  = (int*)  alloc(256);
    const size_t commonEnd = off;

    // Phase-shared buffers (P): used by expert loop and chunked-shared.
    bf16* Wu   = (bf16*)alloc((size_t)I * Cdim * 2);     // 5.77 MB
    bf16* WgWd = (bf16*)alloc((size_t)I * Cdim * 2);     // aliased gate/down
    bf16* Hc   = (bf16*)alloc((size_t)N * I * 2);        // 23.1 MB
    if (off > ws_size) return;

    cvtx<<<4096, 256, 0, stream>>>(x, xb, (long)N * Cdim / 4);
    router<<<N / 4, 256, 0, stream>>>(x, gw, segw, tidx, tw, sg, Cdim);
    build_lists<<<E, 256, 0, stream>>>(tidx, tw, tok, wl, cnt, N);

    // ---------------- shared expert FIRST (beta=0 covers d_out) -------------
    const size_t bigSharedNeed = commonEnd
        + 2 * (size_t)SI * Cdim * 2 + (size_t)N * SI * 2 + 4096;  // ~173 MB
    if (ws_size >= bigSharedNeed) {
        size_t qoff = commonEnd;   // region Q overlaps P (different phase, stream-serial)
        auto qalloc = [&](size_t bytes) { char* p = ws + qoff; qoff += (bytes + 255) & ~(size_t)255; return p; };
        bf16* WgsWds = (bf16*)qalloc((size_t)SI * Cdim * 2);
        bf16* Wus    = (bf16*)qalloc((size_t)SI * Cdim * 2);
        bf16* Hcs    = (bf16*)qalloc((size_t)N * SI * 2);
        tcvt<<<dim3(SI / 64, Cdim / 64), 256, 0, stream>>>(sgw, WgsWds, SI, (long)Cdim);
        tcvt<<<dim3(SI / 64, Cdim / 64), 256, 0, stream>>>(suw, Wus,    SI, (long)Cdim);
        dual_gemm<<<dim3(N / 128, SI / 64), 256, 0, stream>>>(xb, nullptr, nullptr, N,
                WgsWds, Wus, Hcs, (long)SI, sg, Cdim);
        tcvt<<<dim3(Cdim / 64, SI / 64), 256, 0, stream>>>(sdw, WgsWds, Cdim, (long)SI);
        gemm_down<<<dim3(Cdim / 128, N / 128), 256, 0, stream>>>(Hcs, WgsWds, out,
                nullptr, nullptr, N, SI, (long)Cdim, 0);
    } else {
        for (int s = 0; s < SI / I; s++) {               // 4 chunks of 1408
            const long col0 = (long)s * I;
            tcvt<<<dim3(I / 64, Cdim / 64), 256, 0, stream>>>(sgw + col0, WgWd, SI, (long)Cdim);
            tcvt<<<dim3(I / 64, Cdim / 64), 256, 0, stream>>>(suw + col0, Wu,   SI, (long)Cdim);
            dual_gemm<<<dim3(N / 128, I / 64), 256, 0, stream>>>(xb, nullptr, nullptr, N,
                    WgWd, Wu, Hc, (long)I, sg, Cdim);
            tcvt<<<dim3(Cdim / 64, I / 64), 256, 0, stream>>>(sdw + col0 * Cdim, WgWd, Cdim, (long)I);
            gemm_down<<<dim3(Cdim / 128, N / 128), 256, 0, stream>>>(Hc, WgWd, out,
                    nullptr, nullptr, N, I, (long)Cdim, s > 0);
        }
    }

    // ---------------- routed experts, fixed order (deterministic) -----------
    for (int e = 0; e < E; e++) {
        const float* gsrc = egw + (long)e * Cdim * I;    // [C][I]
        const float* usrc = euw + (long)e * Cdim * I;
        const float* dsrc = edw + (long)e * I * Cdim;    // [I][C]
        tcvt<<<dim3(I / 64, Cdim / 64), 256, 0, stream>>>(gsrc, WgWd, I, (long)Cdim);
        tcvt<<<dim3(I / 64, Cdim / 64), 256, 0, stream>>>(usrc, Wu,   I, (long)Cdim);
        dual_gemm<<<dim3(N / 128, I / 64), 256, 0, stream>>>(xb, tok + (long)e * N,
                cnt + e, 0, WgWd, Wu, Hc, (long)I, wl + (long)e * N, Cdim);
        tcvt<<<dim3(Cdim / 64, I / 64), 256, 0, stream>>>(dsrc, WgWd, Cdim, (long)I);
        gemm_down<<<dim3(Cdim / 128, N / 128), 256, 0, stream>>>(Hc, WgWd, out,
                tok + (long)e * N, cnt + e, 0, I, (long)Cdim, 1);
    }
}

// Round 4
// 1642.062 us; speedup vs baseline: 1.2814x; 1.0500x over previous
//
#include <hip/hip_runtime.h>
#include <hip/hip_bf16.h>
#include <stdint.h>

// R4: consolidation round. z-batched weight conversion, z-batched expert
// gate/up GEMMs (2 batches of 4 experts, 196 MB plan < proven 208 MB ws),
// sequential expert down-GEMMs (deterministic accumulation). GEMM cores
// unchanged from R3 (verified: MfmaUtil 54%, 0 bank conflicts).

typedef float f32x4 __attribute__((ext_vector_type(4)));
typedef int   i32x4 __attribute__((ext_vector_type(4)));
typedef __hip_bfloat16 bf16;

#define DEV __device__ __forceinline__

DEV void mfma16(f32x4& c, const i32x4& a, const i32x4& b) {
    asm("v_mfma_f32_16x16x32_bf16 %0, %1, %2, %0" : "+v"(c) : "v"(a), "v"(b));
}

// Direct stage: [ROWS][64] bf16 tile (row stride ldK elems) -> LDS linear,
// T2 XOR swizzle applied on the global source (rule #21).
template<int ROWS>
DEV void stage(const bf16* gtile, long ldK, char* lds, int tid) {
    const int wid = tid >> 6, lane = tid & 63;
    const int swz = ((lane & 7) ^ (lane >> 3)) << 4;
    constexpr int NISS = (ROWS * 128) / 4096;
    #pragma unroll
    for (int i = 0; i < NISS; i++) {
        const int o = i * 4096 + wid * 1024;
        const int row = (o >> 7) + (lane >> 3);
        const char* ga = (const char*)gtile + (long)row * (ldK * 2) + swz;
        __builtin_amdgcn_global_load_lds(
            (const __attribute__((address_space(1))) void*)ga,
            (__attribute__((address_space(3))) void*)(lds + o), 16, 0, 0);
    }
}

// Indirect stage: per-lane row byte-offsets precomputed (gathered rows).
template<int ROWS>
DEV void stage_idx(const char* base, const long* roff, int ktb, char* lds,
                   int tid, int swz) {
    const int wid = tid >> 6;
    constexpr int NISS = (ROWS * 128) / 4096;
    #pragma unroll
    for (int i = 0; i < NISS; i++) {
        const int o = i * 4096 + wid * 1024;
        const char* ga = base + roff[i] + ktb + swz;
        __builtin_amdgcn_global_load_lds(
            (const __attribute__((address_space(1))) void*)ga,
            (__attribute__((address_space(3))) void*)(lds + o), 16, 0, 0);
    }
}

DEV i32x4 ldsfrag(const char* lds, int row, int kbyte) {
    const int off = (row << 7) + (kbyte ^ ((row & 7) << 4));
    return *(const i32x4*)(lds + off);
}

// ---------------- transpose + fp32->bf16 convert (z-batched) ----------------
// dst[(cb+c)*dld + rb+tx] = src[(rb+r)*Cd + cb+tx]; z adds sz/dz elems.
__global__ __launch_bounds__(256) void tcvt(const float* __restrict__ src,
        bf16* __restrict__ dst, int Cd, long dld, long sz, long dz) {
    __shared__ float t[64][65];
    const long z = blockIdx.z;
    src += z * sz; dst += z * dz;
    const int cb = blockIdx.x * 64, rb = blockIdx.y * 64;
    const int tx = threadIdx.x & 63, ty = threadIdx.x >> 6;
    #pragma unroll
    for (int i = 0; i < 16; i++) {
        const int r = ty + i * 4;
        t[r][tx] = src[(long)(rb + r) * Cd + cb + tx];
    }
    __syncthreads();
    #pragma unroll
    for (int i = 0; i < 16; i++) {
        const int c = ty + i * 4;
        dst[(long)(cb + c) * dld + rb + tx] = __float2bfloat16(t[tx][c]);
    }
}

// ---------------- x fp32 -> bf16 ----------------
__global__ __launch_bounds__(256) void cvtx(const float* __restrict__ x,
        bf16* __restrict__ xb, long n4) {
    long i = (long)blockIdx.x * blockDim.x + threadIdx.x;
    const long stride = (long)gridDim.x * blockDim.x;
    for (; i < n4; i += stride) {
        const float4 v = ((const float4*)x)[i];
        union { bf16 h[4]; ushort4 u; } cu;
        cu.h[0] = __float2bfloat16(v.x); cu.h[1] = __float2bfloat16(v.y);
        cu.h[2] = __float2bfloat16(v.z); cu.h[3] = __float2bfloat16(v.w);
        ((ushort4*)xb)[i] = cu.u;
    }
}

// ---------------- router: fp32 logits, softmax, top-4, renorm ----------------
__global__ __launch_bounds__(256) void router(const float* __restrict__ x,
        const float* __restrict__ gw, const float* __restrict__ segw,
        int* __restrict__ tidx, float* __restrict__ tw,
        float* __restrict__ sg, int C) {
    const int lane = threadIdx.x & 63;
    const long t = (long)blockIdx.x * 4 + (threadIdx.x >> 6);
    const float* xr = x + t * C;
    float a[9];
    #pragma unroll
    for (int e = 0; e < 9; e++) a[e] = 0.f;
    for (int c = lane; c < C; c += 64) {
        const float xv = xr[c];
        const float4* g4 = (const float4*)(gw + (long)c * 8);
        const float4 g0 = g4[0], g1 = g4[1];
        a[0] += xv * g0.x; a[1] += xv * g0.y; a[2] += xv * g0.z; a[3] += xv * g0.w;
        a[4] += xv * g1.x; a[5] += xv * g1.y; a[6] += xv * g1.z; a[7] += xv * g1.w;
        a[8] += xv * segw[c];
    }
    #pragma unroll
    for (int e = 0; e < 9; e++) {
        #pragma unroll
        for (int o = 32; o; o >>= 1) a[e] += __shfl_xor(a[e], o, 64);
    }
    if (lane == 0) {
        float m = a[0];
        #pragma unroll
        for (int e = 1; e < 8; e++) m = fmaxf(m, a[e]);
        float p[8]; float s = 0.f;
        #pragma unroll
        for (int e = 0; e < 8; e++) { p[e] = expf(a[e] - m); s += p[e]; }
        #pragma unroll
        for (int e = 0; e < 8; e++) p[e] /= s;
        bool used[8] = {false,false,false,false,false,false,false,false};
        float wsum = 0.f; int idx[4]; float wv[4];
        for (int k = 0; k < 4; k++) {       // strict > : lowest index on ties
            float best = -1.f; int bi = 0;
            for (int e = 0; e < 8; e++)
                if (!used[e] && p[e] > best) { best = p[e]; bi = e; }
            used[bi] = true; idx[k] = bi; wv[k] = best; wsum += best;
        }
        int4 iv; float4 wv4;
        iv.x = idx[0]; iv.y = idx[1]; iv.z = idx[2]; iv.w = idx[3];
        wv4.x = wv[0] / wsum; wv4.y = wv[1] / wsum;
        wv4.z = wv[2] / wsum; wv4.w = wv[3] / wsum;
        ((int4*)tidx)[t] = iv;
        ((float4*)tw)[t] = wv4;
        sg[t] = 1.f / (1.f + expf(-a[8]));
    }
}

// ---------------- per-expert ordered token lists (deterministic) ------------
__global__ __launch_bounds__(256) void build_lists(const int* __restrict__ tidx,
        const float* __restrict__ tw, int* __restrict__ tok,
        float* __restrict__ wl, int* __restrict__ cnt, int N) {
    const int e = blockIdx.x;                 // 8 blocks
    const int tid = threadIdx.x;
    const int per = N / 256;
    __shared__ int csum[256];
    int c = 0;
    for (int i = 0; i < per; i++) {
        const int4 id4 = ((const int4*)tidx)[tid * per + i];
        if (id4.x == e || id4.y == e || id4.z == e || id4.w == e) c++;
    }
    csum[tid] = c;
    __syncthreads();
    for (int o = 1; o < 256; o <<= 1) {
        const int v = (tid >= o) ? csum[tid - o] : 0;
        __syncthreads();
        csum[tid] += v;
        __syncthreads();
    }
    int pos = csum[tid] - c;
    if (tid == 255) cnt[e] = csum[255];
    for (int i = 0; i < per; i++) {
        const int t = tid * per + i;
        const int4   id4 = ((const int4*)tidx)[t];
        const float4 w4  = ((const float4*)tw)[t];
        float w = 0.f; int hit = 0;
        if      (id4.x == e) { w = w4.x; hit = 1; }
        else if (id4.y == e) { w = w4.y; hit = 1; }
        else if (id4.z == e) { w = w4.z; hit = 1; }
        else if (id4.w == e) { w = w4.w; hit = 1; }
        if (hit) { tok[(long)e * N + pos] = t; wl[(long)e * N + pos] = w; pos++; }
    }
}

// -------- fused gate+up GEMM (z-batched): H = silu(xg)*xu*sc ---------------
// Tile 128x64, BK=64, 4 waves (2x2). tok!=null -> A rows gathered per z.
__global__ __launch_bounds__(256) void dual_gemm(const bf16* __restrict__ A,
        const int* __restrict__ tok, long tokz,
        const int* __restrict__ cnt, int Mfix,
        const bf16* __restrict__ BG0, const bf16* __restrict__ BU0, long bz,
        bf16* __restrict__ H0, long hld, long hz,
        const float* __restrict__ sc0, long scz, int K) {
    __shared__ __align__(128) char Al[16384];
    __shared__ __align__(128) char Gl[8192];
    __shared__ __align__(128) char Ul[8192];
    const int z = blockIdx.z;
    const int Me = cnt ? cnt[z] : Mfix;
    const long m0 = (long)blockIdx.x * 128;
    if (m0 >= Me) return;
    const int* ridx = tok ? tok + (long)z * tokz : nullptr;
    const bf16* BG = BG0 + (long)z * bz;
    const bf16* BU = BU0 + (long)z * bz;
    bf16* H = H0 + (long)z * hz;
    const float* sc = sc0 + (long)z * scz;
    const int tid = threadIdx.x, lane = tid & 63, wid = tid >> 6;
    const long n0 = (long)blockIdx.y * 64;
    const int wm = (wid >> 1) * 64, wn = (wid & 1) * 32;
    const int l15 = lane & 15, lhi = lane >> 4;
    const int swz = ((lane & 7) ^ (lane >> 3)) << 4;
    long roffA[4];
    #pragma unroll
    for (int i = 0; i < 4; i++) {
        const int rit = ((i * 4096 + wid * 1024) >> 7) + (lane >> 3);
        int g = (int)m0 + rit;
        if (ridx) g = ridx[g < Me ? g : Me - 1];
        roffA[i] = (long)g * (K * 2);
    }
    f32x4 ag[4][2] = {}; f32x4 au[4][2] = {};
    for (int kt = 0; kt < K; kt += 64) {
        stage_idx<128>((const char*)A, roffA, kt * 2, Al, tid, swz);
        stage<64>(BG + n0 * K + kt, (long)K, Gl, tid);
        stage<64>(BU + n0 * K + kt, (long)K, Ul, tid);
        __syncthreads();
        #pragma unroll
        for (int ks = 0; ks < 2; ks++) {
            const int kb = ks * 64 + lhi * 16;
            i32x4 af[4], bg[2], bu[2];
            #pragma unroll
            for (int mi = 0; mi < 4; mi++) af[mi] = ldsfrag(Al, wm + mi * 16 + l15, kb);
            #pragma unroll
            for (int ni = 0; ni < 2; ni++) {
                bg[ni] = ldsfrag(Gl, wn + ni * 16 + l15, kb);
                bu[ni] = ldsfrag(Ul, wn + ni * 16 + l15, kb);
            }
            #pragma unroll
            for (int mi = 0; mi < 4; mi++) {
                #pragma unroll
                for (int ni = 0; ni < 2; ni++) {
                    mfma16(ag[mi][ni], af[mi], bg[ni]);
                    mfma16(au[mi][ni], af[mi], bu[ni]);
                }
            }
        }
        __syncthreads();
    }
    asm volatile("s_nop 7\n\ts_nop 7\n\ts_nop 7");
    #pragma unroll
    for (int mi = 0; mi < 4; mi++) {
        #pragma unroll
        for (int r = 0; r < 4; r++) {
            const int pos = (int)m0 + wm + mi * 16 + lhi * 4 + r;
            if (pos < Me) {
                const float s = sc[pos];
                #pragma unroll
                for (int ni = 0; ni < 2; ni++) {
                    const float gv = ag[mi][ni][r], uv = au[mi][ni][r];
                    const float h = (gv / (1.f + expf(-gv))) * uv * s;
                    H[(long)pos * hld + n0 + wn + ni * 16 + l15] = __float2bfloat16(h);
                }
            }
        }
    }
}

// ------ down GEMM: C[row(pos)] (+)= A[pos,:K] * BT^T, scatter rows ----------
__global__ __launch_bounds__(256) void gemm_down(const bf16* __restrict__ A,
        const bf16* __restrict__ BT, float* __restrict__ C,
        const int* __restrict__ ridx, const int* __restrict__ cntp, int Mfix,
        int K, long ldc, int beta) {
    __shared__ __align__(128) char Al[16384];
    __shared__ __align__(128) char Bl[16384];
    const int Me = cntp ? *cntp : Mfix;
    const long m0 = (long)blockIdx.y * 128;
    if (m0 >= Me) return;
    const int tid = threadIdx.x, lane = tid & 63, wid = tid >> 6;
    const long n0 = (long)blockIdx.x * 128;
    const int wm = (wid >> 1) * 64, wn = (wid & 1) * 64;
    const int l15 = lane & 15, lhi = lane >> 4;
    f32x4 acc[4][4] = {};
    for (int kt = 0; kt < K; kt += 64) {
        stage<128>(A  + m0 * K + kt, (long)K, Al, tid);
        stage<128>(BT + n0 * K + kt, (long)K, Bl, tid);
        __syncthreads();
        #pragma unroll
        for (int ks = 0; ks < 2; ks++) {
            const int kb = ks * 64 + lhi * 16;
            i32x4 af[4], bfr[4];
            #pragma unroll
            for (int mi = 0; mi < 4; mi++) af[mi]  = ldsfrag(Al, wm + mi * 16 + l15, kb);
            #pragma unroll
            for (int ni = 0; ni < 4; ni++) bfr[ni] = ldsfrag(Bl, wn + ni * 16 + l15, kb);
            #pragma unroll
            for (int mi = 0; mi < 4; mi++) {
                #pragma unroll
                for (int ni = 0; ni < 4; ni++) mfma16(acc[mi][ni], af[mi], bfr[ni]);
            }
        }
        __syncthreads();
    }
    asm volatile("s_nop 7\n\ts_nop 7\n\ts_nop 7");
    #pragma unroll
    for (int mi = 0; mi < 4; mi++) {
        #pragma unroll
        for (int r = 0; r < 4; r++) {
            const int pos = (int)m0 + wm + mi * 16 + lhi * 4 + r;
            if (pos < Me) {
                const long orow = ridx ? (long)ridx[pos] : (long)pos;
                #pragma unroll
                for (int ni = 0; ni < 4; ni++) {
                    const long ci = orow * ldc + n0 + wn + ni * 16 + l15;
                    float v = acc[mi][ni][r];
                    if (beta) v += C[ci];
                    C[ci] = v;
                }
            }
        }
    }
}

extern "C" void kernel_launch(void* const* d_in, const int* in_sizes, int n_in,
                              void* d_out, int out_size, void* d_ws, size_t ws_size,
                              hipStream_t stream) {
    const int N = 8192, Cdim = 2048, E = 8, I = 1408, SI = 5632;

    const float* x    = (const float*)d_in[0];
    const float* gw   = (const float*)d_in[1];
    const float* egw  = (const float*)d_in[2];
    const float* euw  = (const float*)d_in[3];
    const float* edw  = (const float*)d_in[4];
    const float* sgw  = (const float*)d_in[5];
    const float* suw  = (const float*)d_in[6];
    const float* sdw  = (const float*)d_in[7];
    const float* segw = (const float*)d_in[8];
    float* out = (float*)d_out;

    char* ws = (char*)d_ws;
    size_t off = 0;
    auto alloc = [&](size_t bytes) { char* p = ws + off; off += (bytes + 255) & ~(size_t)255; return p; };

    bf16*  xb   = (bf16*) alloc((size_t)N * Cdim * 2);   // 33.6 MB
    int*   tidx = (int*)  alloc((size_t)N * 4 * 4);
    float* tw   = (float*)alloc((size_t)N * 4 * 4);
    float* sg   = (float*)alloc((size_t)N * 4);
    int*   tok  = (int*)  alloc((size_t)E * N * 4);
    float* wl   = (float*)alloc((size_t)E * N * 4);
    int*   cnt  = (int*)  alloc(256);

    // Three weight slots (each SI*C = 4*I*C elems) + one H region (N*SI = 4*N*I).
    const size_t WSLOT = (size_t)SI * Cdim * 2;          // 23.1 MB
    bf16* Wa = (bf16*)alloc(WSLOT);
    bf16* Wb = (bf16*)alloc(WSLOT);
    bf16* Wc = (bf16*)alloc(WSLOT);
    bf16* Hc = (bf16*)alloc((size_t)N * SI * 2);         // 92.3 MB
    if (off > ws_size) return;                           // 196 MB total (ws>=208 proven)

    cvtx<<<4096, 256, 0, stream>>>(x, xb, (long)N * Cdim / 4);
    router<<<N / 4, 256, 0, stream>>>(x, gw, segw, tidx, tw, sg, Cdim);
    build_lists<<<E, 256, 0, stream>>>(tidx, tw, tok, wl, cnt, N);

    // ---------------- shared expert (beta=0 covers d_out) -------------------
    tcvt<<<dim3(SI / 64, Cdim / 64, 1), 256, 0, stream>>>(sgw, Wa, SI, (long)Cdim, 0, 0);
    tcvt<<<dim3(SI / 64, Cdim / 64, 1), 256, 0, stream>>>(suw, Wb, SI, (long)Cdim, 0, 0);
    tcvt<<<dim3(Cdim / 64, SI / 64, 1), 256, 0, stream>>>(sdw, Wc, Cdim, (long)SI, 0, 0);
    dual_gemm<<<dim3(N / 128, SI / 64, 1), 256, 0, stream>>>(xb,
            nullptr, 0, nullptr, N, Wa, Wb, 0, Hc, (long)SI, 0, sg, 0, Cdim);
    gemm_down<<<dim3(Cdim / 128, N / 128), 256, 0, stream>>>(Hc, Wc, out,
            nullptr, nullptr, N, SI, (long)Cdim, 0);

    // ---------------- routed experts: 2 batches of 4 ------------------------
    for (int b = 0; b < 2; b++) {
        const int e0 = b * 4;
        tcvt<<<dim3(I / 64, Cdim / 64, 4), 256, 0, stream>>>(
                egw + (long)e0 * Cdim * I, Wa, I, (long)Cdim,
                (long)Cdim * I, (long)I * Cdim);
        tcvt<<<dim3(I / 64, Cdim / 64, 4), 256, 0, stream>>>(
                euw + (long)e0 * Cdim * I, Wb, I, (long)Cdim,
                (long)Cdim * I, (long)I * Cdim);
        tcvt<<<dim3(Cdim / 64, I / 64, 4), 256, 0, stream>>>(
                edw + (long)e0 * I * Cdim, Wc, Cdim, (long)I,
                (long)I * Cdim, (long)Cdim * I);
        dual_gemm<<<dim3(N / 128, I / 64, 4), 256, 0, stream>>>(xb,
                tok + (long)e0 * N, (long)N, cnt + e0, 0,
                Wa, Wb, (long)I * Cdim,
                Hc, (long)I, (long)N * I,
                wl + (long)e0 * N, (long)N, Cdim);
        for (int z = 0; z < 4; z++) {
            gemm_down<<<dim3(Cdim / 128, N / 128), 256, 0, stream>>>(
                    Hc + (long)z * N * I, Wc + (long)z * Cdim * I, out,
                    tok + (long)(e0 + z) * N, cnt + e0 + z, 0,
                    I, (long)Cdim, 1);
        }
    }
}